// Round 18
// baseline (622.057 us; speedup 1.0000x reference)
//
#include <hip/hip_runtime.h>
#include <hip/hip_bf16.h>

typedef __attribute__((ext_vector_type(8))) short short8;
typedef __attribute__((ext_vector_type(4))) float f32x4;

#define CH 128
#define H 256
#define W 512
#define PH 258
#define PW 516
#define NTAPS 13
#define P_BYTES (PH * PW * CH * 2)       // 34,080,768 per slab
#define P_SHORTS (PH * PW * CH)
#define KK_SHORTS (PH * PW * 32)         // one 32-ic chunk of a slab
#define CHW (CH * H * W)

// per-chunk LDS buffer: 6 rows x 544 granules(16B) = 3264 -> pad 3328 (52 loads)
#define GRAN_PER_ROW 544                 // 68 px-pairs x 8 granules
#define NLOADS 52
#define BUF_SHORTS (3328 * 8)            // 26624 shorts = 53,248 B
#define ROW_SHORTS (GRAN_PER_ROW * 8)    // 4352 shorts per LDS row

#define GLD_LDS16(g, l)                                                        \
  __builtin_amdgcn_global_load_lds(                                            \
      (const __attribute__((address_space(1))) void*)(g),                      \
      (__attribute__((address_space(3))) void*)(l), 16, 0, 0)

// ---- kernel 0: zero pad borders of all 8 kk-major P slabs (per call) -------
// P slab layout: [kk=4][PH][PW][32 ic] bf16  (uints: 16 per px-record)
__global__ void zero_pads(unsigned int* __restrict__ Pd) {
    int row  = blockIdx.x;               // 0..257
    int slab = blockIdx.y;               // 0..7
    unsigned int* base = Pd + (size_t)slab * (P_SHORTS / 2);
    int tid = threadIdx.x;
    if (row < 2) {                       // full top rows, each kk chunk
#pragma unroll
        for (int kk = 0; kk < 4; ++kk) {
            unsigned int* r = base + (size_t)kk * (KK_SHORTS / 2) +
                              (size_t)row * (PW * 16);
            for (int i = tid; i < PW * 16; i += 256) r[i] = 0u;
        }
    } else {                             // side cols {0,1,514,515} x 4 kk
        int kk  = tid >> 6;
        int seg = (tid >> 4) & 3;
        int col = seg < 2 ? seg : 512 + seg;
        int u   = tid & 15;
        base[(size_t)kk * (KK_SHORTS / 2) + ((size_t)row * PW + col) * 16 + u] = 0u;
    }
}

// ---- kernel 1: premask + cast weights into 16x16 MFMA-fragment order -------
// Wt2 element idx = fragIdx*512 + lane*8 + e, fragIdx = (t*8 + ob)*4 + kcg
// lane: oc = ob*16 + (lane&15), ic = kcg*32 + (lane>>4)*8 + e
__global__ void premask_weights(const float* __restrict__ w,
                                __hip_bfloat16* __restrict__ Wt2) {
    int idx  = blockIdx.x * 256 + threadIdx.x;   // 13*8*4*512 = 212992
    int frag = idx >> 9;
    int r    = idx & 511;
    int l    = r >> 3;
    int e    = r & 7;
    int t    = frag >> 5;
    int ob   = (frag >> 2) & 7;
    int kcg  = frag & 3;
    int oc   = ob * 16 + (l & 15);
    int ic   = kcg * 32 + (l >> 4) * 8 + e;
    int ky   = t < 5 ? 0 : (t < 10 ? 1 : 2);
    int kx   = t - ky * 5;
    float v  = w[(oc * CH + ic) * 25 + ky * 5 + kx];
    if (t == 12 && ((ic >> 4) > (oc >> 4))) v = 0.f;   // group-causal center tap
    Wt2[idx] = __float2bfloat16(v);
}

// ---- kernel 2: NCHW fp32 -> padded kk-major NHWC bf16, all 8 n -------------
__global__ void transpose_pad_all(const float* __restrict__ x,
                                  __hip_bfloat16* __restrict__ Pbase) {
    __shared__ float tile[32][33];
    const float* xn = x + (size_t)blockIdx.z * CHW;
    unsigned short* P = (unsigned short*)(Pbase + (size_t)blockIdx.z * P_SHORTS);
    int h  = blockIdx.y;
    int wt = blockIdx.x & 15;
    int ct = blockIdx.x >> 4;            // 32-ic chunk == kk
    int tx = threadIdx.x & 31;
    int ty = threadIdx.x >> 5;
#pragma unroll
    for (int r = 0; r < 4; ++r) {
        int c = ct * 32 + ty + r * 8;
        tile[ty + r * 8][tx] = xn[(c * H + h) * W + wt * 32 + tx];
    }
    __syncthreads();
    int wl = threadIdx.x >> 3;
    int cq = threadIdx.x & 7;
    union { ushort4 u; __hip_bfloat16 hh[4]; } v;
    v.hh[0] = __float2bfloat16(tile[cq * 4 + 0][wl]);
    v.hh[1] = __float2bfloat16(tile[cq * 4 + 1][wl]);
    v.hh[2] = __float2bfloat16(tile[cq * 4 + 2][wl]);
    v.hh[3] = __float2bfloat16(tile[cq * 4 + 3][wl]);
    *reinterpret_cast<ushort4*>(
        P + (size_t)ct * KK_SHORTS +
        ((size_t)(h + 2) * PW + (wt * 32 + wl + 2)) * 32 + cq * 4) = v.u;
}

// ---- kernel 3: MFMA conv, all n; 128 oc x 4h x 128 w per block -------------
// R17 data path (kk-major P, pairing swizzle, XCD z-swizzle, row-sharing)
// + 5-phase/chunk m201-style schedule: per kx phase
//   {stage issue | B ds_reads | ky0 A} ; s_barrier ; lgkmcnt(0)+sched_barrier ;
//   setprio(1) ; nky x 32 MFMA (ky1/ky2 A inline) ; setprio(0) ; s_barrier.
// Stage loads fly across phases; drained only at chunk-end __syncthreads.
__global__ __launch_bounds__(512, 2)
void conv_mfma_all(const __hip_bfloat16* __restrict__ Pbase,
                   const __hip_bfloat16* __restrict__ Wt2,
                   const float* __restrict__ bias,
                   const float* __restrict__ slope,
                   float* __restrict__ out) {
    __shared__ short lds[2 * BUF_SHORTS];   // 106,496 B -> 1 block/CU
    // XCD-chunked block swizzle: 2048 blocks, XCD k gets [k*256,(k+1)*256)
    int d   = blockIdx.x;
    int lid = (d & 7) * 256 + (d >> 3);
    int bz  = lid >> 8;                  // n slab (one per XCD)
    int by  = (lid >> 2) & 63;
    int bx  = lid & 3;
    const __hip_bfloat16* P = Pbase + (size_t)bz * P_SHORTS;
    float* outn = out + (size_t)bz * CHW;
    int h0    = by << 2;
    int w0    = bx << 7;
    int tid   = threadIdx.x;
    int lane  = tid & 63;
    int wv    = tid >> 6;                // 0..7
    int l15   = lane & 15;
    int khi   = lane >> 4;               // 0..3
    int ohf   = wv & 1;                  // oc half
    int hp    = (wv >> 1) & 1;           // h pair (rows 0-1 or 2-3)
    int pxh   = wv >> 2;                 // px half

    f32x4 acc[4][2][4];                  // [mi][o][ni] = 128 f32
#pragma unroll
    for (int mi = 0; mi < 4; ++mi)
#pragma unroll
        for (int o = 0; o < 2; ++o)
#pragma unroll
            for (int ni = 0; ni < 4; ++ni)
                acc[mi][o][ni] = (f32x4){0.f, 0.f, 0.f, 0.f};

    const short* Wt2s = (const short*)Wt2;

    // ---- stage source offsets (shorts within a kk chunk), pairing-swizzled --
    int stoff[7];
#pragma unroll
    for (int i = 0; i < 7; ++i) {
        int s    = wv + i * 8;           // 0..55; only s<52 used
        int g64  = (s << 6) + lane;      // granule 0..3583
        int row  = (g64 >= 544) + (g64 >= 1088) + (g64 >= 1632) +
                   (g64 >= 2176) + (g64 >= 2720) + (g64 >= 3264);
        int rowc = row < 6 ? row : 5;
        int G    = g64 - row * GRAN_PER_ROW;
        int pair = G >> 3;
        int qd   = (G & 7) ^ (pair & 7);
        int px   = pair * 2 + (qd >> 2);
        int chk  = qd & 3;
        int pxc  = px < 132 ? px : 131;  // clamp unused slots
        stoff[i] = ((h0 + rowc) * PW + (w0 + pxc)) * 32 + chk * 8;
    }
    // per-lane B offsets (shorts) for each kx, within a row (pxh folded in)
    int bq[5];
#pragma unroll
    for (int kx = 0; kx < 5; ++kx) {
        int pxb  = pxh * 64 + kx + l15;
        int pair = pxb >> 1;
        bq[kx] = ((pair << 3) + ((((pxb & 1) << 2) | khi) ^ (pair & 7))) << 3;
    }

    // one stage load (index i) of chunk kk into buffer half bsel
    auto stage1 = [&](int kk, int bsel, int i) {
        int s = wv + i * 8;
        if (s < NLOADS)
            GLD_LDS16(P + (size_t)kk * KK_SHORTS + stoff[i],
                      (char*)lds + bsel * (BUF_SHORTS * 2) + (s << 10));
    };

#pragma unroll
    for (int i = 0; i < 7; ++i) stage1(0, 0, i);
    __syncthreads();

    for (int kk = 0; kk < 4; ++kk) {
        const int cur = kk & 1;
        const short* apb = Wt2s + ((ohf * 16 + kk) << 9) + (lane << 3);
        const short* bb  = lds + cur * BUF_SHORTS + (hp * 2) * ROW_SHORTS;

#pragma unroll
        for (int kx = 0; kx < 5; ++kx) {
            const int nky = (kx < 3) ? 3 : 2;   // ky=2 only for kx<3
            // ---- load section: stage issue + B rows + ky0 A ----------------
            if (kk < 3) {
                if (kx == 0)      { stage1(kk + 1, cur ^ 1, 0);
                                    stage1(kk + 1, cur ^ 1, 1); }
                else if (kx == 1) { stage1(kk + 1, cur ^ 1, 2);
                                    stage1(kk + 1, cur ^ 1, 3); }
                else              { stage1(kk + 1, cur ^ 1, kx + 2); }
            }
            short8 B[4][4];                      // rows 0..nky
#pragma unroll
            for (int r = 0; r < 4; ++r) {
                if (r > nky) break;
#pragma unroll
                for (int ni = 0; ni < 4; ++ni)
                    B[r][ni] = *reinterpret_cast<const short8*>(
                        bb + r * ROW_SHORTS + bq[kx] + ni * 512);
            }
            short8 a0[4];
#pragma unroll
            for (int mi = 0; mi < 4; ++mi)
                a0[mi] = *reinterpret_cast<const short8*>(
                    apb + (0 * 5 + kx) * 16384 + mi * 2048);
            // ---- phase barrier + waits (rule 18) ---------------------------
            __builtin_amdgcn_s_barrier();
            asm volatile("s_waitcnt lgkmcnt(0)" ::: "memory");
            __builtin_amdgcn_sched_barrier(0);
            // ---- MFMA cluster ----------------------------------------------
            __builtin_amdgcn_s_setprio(1);
#pragma unroll
            for (int mi = 0; mi < 4; ++mi)
#pragma unroll
                for (int o = 0; o < 2; ++o)
#pragma unroll
                    for (int ni = 0; ni < 4; ++ni)
                        acc[mi][o][ni] = __builtin_amdgcn_mfma_f32_16x16x32_bf16(
                            a0[mi], B[0 + o][ni], acc[mi][o][ni], 0, 0, 0);
#pragma unroll
            for (int ky = 1; ky < 3; ++ky) {
                if (ky >= nky) break;
                short8 a[4];
#pragma unroll
                for (int mi = 0; mi < 4; ++mi)
                    a[mi] = *reinterpret_cast<const short8*>(
                        apb + (ky * 5 + kx) * 16384 + mi * 2048);
#pragma unroll
                for (int mi = 0; mi < 4; ++mi)
#pragma unroll
                    for (int o = 0; o < 2; ++o)
#pragma unroll
                        for (int ni = 0; ni < 4; ++ni)
                            acc[mi][o][ni] = __builtin_amdgcn_mfma_f32_16x16x32_bf16(
                                a[mi], B[ky + o][ni], acc[mi][o][ni], 0, 0, 0);
            }
            __builtin_amdgcn_s_setprio(0);
            __builtin_amdgcn_s_barrier();
        }
        __syncthreads();   // drains stage prefetch + protects buf reuse
    }

    // ---- epilogue: bias + per-channel leaky relu ----------------------------
#pragma unroll
    for (int mi = 0; mi < 4; ++mi) {
        int ocb = ohf * 64 + mi * 16 + 4 * khi;
        f32x4 b4 = *reinterpret_cast<const f32x4*>(bias + ocb);
        f32x4 s4 = *reinterpret_cast<const f32x4*>(slope + ocb);
#pragma unroll
        for (int o = 0; o < 2; ++o) {
            int hrow = h0 + hp * 2 + o;
#pragma unroll
            for (int i = 0; i < 4; ++i) {
                float* orow = outn + ((ocb + i) * H + hrow) * W + w0 + pxh * 64;
#pragma unroll
                for (int ni = 0; ni < 4; ++ni) {
                    float v = acc[mi][o][ni][i] + b4[i];
                    v = v > 0.f ? v : s4[i] * v;
                    orow[ni * 16 + l15] = v;
                }
            }
        }
    }
}

extern "C" void kernel_launch(void* const* d_in, const int* in_sizes, int n_in,
                              void* d_out, int out_size, void* d_ws, size_t ws_size,
                              hipStream_t stream) {
    const float* x      = (const float*)d_in[0];
    const float* weight = (const float*)d_in[1];
    const float* bias   = (const float*)d_in[2];
    const float* slope  = (const float*)d_in[3];
    float* out = (float*)d_out;

    __hip_bfloat16* Pbase = (__hip_bfloat16*)d_ws;                 // 8 slabs
    __hip_bfloat16* Wt2   = (__hip_bfloat16*)((char*)d_ws + 8 * (size_t)P_BYTES);

    zero_pads<<<dim3(PH, 8), 256, 0, stream>>>((unsigned int*)d_ws);
    premask_weights<<<832, 256, 0, stream>>>(weight, Wt2);
    transpose_pad_all<<<dim3(64, 256, 8), 256, 0, stream>>>(x, Pbase);
    conv_mfma_all<<<2048, 512, 0, stream>>>(Pbase, Wt2, bias, slope, out);
}

// Round 19
// 554.512 us; speedup vs baseline: 1.1218x; 1.1218x over previous
//
#include <hip/hip_runtime.h>
#include <hip/hip_bf16.h>

typedef __attribute__((ext_vector_type(8))) short short8;
typedef __attribute__((ext_vector_type(4))) float f32x4;

#define CH 128
#define H 256
#define W 512
#define PH 258
#define PW 516
#define NTAPS 13
#define P_BYTES (PH * PW * CH * 2)       // 34,080,768 per slab
#define P_SHORTS (PH * PW * CH)
#define KK_SHORTS (PH * PW * 32)         // one 32-ic chunk of a slab
#define CHW (CH * H * W)

// per-chunk LDS buffer: 6 rows x 544 granules(16B) = 3264 -> pad 3328 (52 loads)
#define GRAN_PER_ROW 544                 // 68 px-pairs x 8 granules
#define NLOADS 52
#define BUF_SHORTS (3328 * 8)            // 26624 shorts = 53,248 B
#define ROW_SHORTS (GRAN_PER_ROW * 8)    // 4352 shorts per LDS row

#define GLD_LDS16(g, l)                                                        \
  __builtin_amdgcn_global_load_lds(                                            \
      (const __attribute__((address_space(1))) void*)(g),                      \
      (__attribute__((address_space(3))) void*)(l), 16, 0, 0)

// ---- kernel 0: zero pad borders of all 8 kk-major P slabs (per call) -------
// P slab layout: [kk=4][PH][PW][32 ic] bf16  (uints: 16 per px-record)
__global__ void zero_pads(unsigned int* __restrict__ Pd) {
    int row  = blockIdx.x;               // 0..257
    int slab = blockIdx.y;               // 0..7
    unsigned int* base = Pd + (size_t)slab * (P_SHORTS / 2);
    int tid = threadIdx.x;
    if (row < 2) {                       // full top rows, each kk chunk
#pragma unroll
        for (int kk = 0; kk < 4; ++kk) {
            unsigned int* r = base + (size_t)kk * (KK_SHORTS / 2) +
                              (size_t)row * (PW * 16);
            for (int i = tid; i < PW * 16; i += 256) r[i] = 0u;
        }
    } else {                             // side cols {0,1,514,515} x 4 kk
        int kk  = tid >> 6;
        int seg = (tid >> 4) & 3;
        int col = seg < 2 ? seg : 512 + seg;
        int u   = tid & 15;
        base[(size_t)kk * (KK_SHORTS / 2) + ((size_t)row * PW + col) * 16 + u] = 0u;
    }
}

// ---- kernel 1: premask + cast weights into 16x16 MFMA-fragment order -------
// Wt2 element idx = fragIdx*512 + lane*8 + e, fragIdx = (t*8 + ob)*4 + kcg
// lane: oc = ob*16 + (lane&15), ic = kcg*32 + (lane>>4)*8 + e
__global__ void premask_weights(const float* __restrict__ w,
                                __hip_bfloat16* __restrict__ Wt2) {
    int idx  = blockIdx.x * 256 + threadIdx.x;   // 13*8*4*512 = 212992
    int frag = idx >> 9;
    int r    = idx & 511;
    int l    = r >> 3;
    int e    = r & 7;
    int t    = frag >> 5;
    int ob   = (frag >> 2) & 7;
    int kcg  = frag & 3;
    int oc   = ob * 16 + (l & 15);
    int ic   = kcg * 32 + (l >> 4) * 8 + e;
    int ky   = t < 5 ? 0 : (t < 10 ? 1 : 2);
    int kx   = t - ky * 5;
    float v  = w[(oc * CH + ic) * 25 + ky * 5 + kx];
    if (t == 12 && ((ic >> 4) > (oc >> 4))) v = 0.f;   // group-causal center tap
    Wt2[idx] = __float2bfloat16(v);
}

// ---- kernel 2: NCHW fp32 -> padded kk-major NHWC bf16, all 8 n -------------
__global__ void transpose_pad_all(const float* __restrict__ x,
                                  __hip_bfloat16* __restrict__ Pbase) {
    __shared__ float tile[32][33];
    const float* xn = x + (size_t)blockIdx.z * CHW;
    unsigned short* P = (unsigned short*)(Pbase + (size_t)blockIdx.z * P_SHORTS);
    int h  = blockIdx.y;
    int wt = blockIdx.x & 15;
    int ct = blockIdx.x >> 4;            // 32-ic chunk == kk
    int tx = threadIdx.x & 31;
    int ty = threadIdx.x >> 5;
#pragma unroll
    for (int r = 0; r < 4; ++r) {
        int c = ct * 32 + ty + r * 8;
        tile[ty + r * 8][tx] = xn[(c * H + h) * W + wt * 32 + tx];
    }
    __syncthreads();
    int wl = threadIdx.x >> 3;
    int cq = threadIdx.x & 7;
    union { ushort4 u; __hip_bfloat16 hh[4]; } v;
    v.hh[0] = __float2bfloat16(tile[cq * 4 + 0][wl]);
    v.hh[1] = __float2bfloat16(tile[cq * 4 + 1][wl]);
    v.hh[2] = __float2bfloat16(tile[cq * 4 + 2][wl]);
    v.hh[3] = __float2bfloat16(tile[cq * 4 + 3][wl]);
    *reinterpret_cast<ushort4*>(
        P + (size_t)ct * KK_SHORTS +
        ((size_t)(h + 2) * PW + (wt * 32 + wl + 2)) * 32 + cq * 4) = v.u;
}

// ---- kernel 3: MFMA conv, all n; 128 oc x 4h x 128 w per block -------------
// Measured-best structure (R17, conv ~393 us): rolled loops, single lds[],
// 2-phase dbuf prefetch, pairing swizzle, XCD z-swizzle, B-row-sharing,
// kk-major P (dense 64B stage reads).
// 8 waves: ohf = wv&1 (oc half), hp = (wv>>1)&1 (h pair), pxh = wv>>2.
__global__ __launch_bounds__(512, 2)
void conv_mfma_all(const __hip_bfloat16* __restrict__ Pbase,
                   const __hip_bfloat16* __restrict__ Wt2,
                   const float* __restrict__ bias,
                   const float* __restrict__ slope,
                   float* __restrict__ out) {
    __shared__ short lds[2 * BUF_SHORTS];   // 106,496 B -> 1 block/CU
    // XCD-chunked block swizzle: 2048 blocks, XCD k gets [k*256,(k+1)*256)
    int d   = blockIdx.x;
    int lid = (d & 7) * 256 + (d >> 3);
    int bz  = lid >> 8;                  // n slab (one per XCD)
    int by  = (lid >> 2) & 63;
    int bx  = lid & 3;
    const __hip_bfloat16* P = Pbase + (size_t)bz * P_SHORTS;
    float* outn = out + (size_t)bz * CHW;
    int h0    = by << 2;
    int w0    = bx << 7;
    int tid   = threadIdx.x;
    int lane  = tid & 63;
    int wv    = tid >> 6;                // 0..7
    int l15   = lane & 15;
    int khi   = lane >> 4;               // 0..3
    int ohf   = wv & 1;                  // oc half
    int hp    = (wv >> 1) & 1;           // h pair (rows 0-1 or 2-3)
    int pxh   = wv >> 2;                 // px half

    f32x4 acc[4][2][4];                  // [mi][o][ni] = 128 f32
#pragma unroll
    for (int mi = 0; mi < 4; ++mi)
#pragma unroll
        for (int o = 0; o < 2; ++o)
#pragma unroll
            for (int ni = 0; ni < 4; ++ni)
                acc[mi][o][ni] = (f32x4){0.f, 0.f, 0.f, 0.f};

    const short* Wt2s = (const short*)Wt2;

    // ---- stage source offsets (shorts within a kk chunk), pairing-swizzled --
    int stoff[7];
#pragma unroll
    for (int i = 0; i < 7; ++i) {
        int s    = wv + i * 8;           // 0..55; only s<52 used
        int g64  = (s << 6) + lane;      // granule 0..3583
        int row  = (g64 >= 544) + (g64 >= 1088) + (g64 >= 1632) +
                   (g64 >= 2176) + (g64 >= 2720) + (g64 >= 3264);
        int rowc = row < 6 ? row : 5;
        int G    = g64 - row * GRAN_PER_ROW;
        int pair = G >> 3;
        int qd   = (G & 7) ^ (pair & 7);
        int px   = pair * 2 + (qd >> 2);
        int chk  = qd & 3;
        int pxc  = px < 132 ? px : 131;  // clamp unused slots
        stoff[i] = ((h0 + rowc) * PW + (w0 + pxc)) * 32 + chk * 8;
    }
    // per-lane B offsets (shorts) for each kx, within a row (pxh folded in)
    int bq[5];
#pragma unroll
    for (int kx = 0; kx < 5; ++kx) {
        int pxb  = pxh * 64 + kx + l15;
        int pair = pxb >> 1;
        bq[kx] = ((pair << 3) + ((((pxb & 1) << 2) | khi) ^ (pair & 7))) << 3;
    }

    auto stage = [&](int kk, int bsel) {
        const __hip_bfloat16* Pk = P + (size_t)kk * KK_SHORTS;
#pragma unroll
        for (int i = 0; i < 7; ++i) {
            int s = wv + i * 8;
            if (s < NLOADS)
                GLD_LDS16(Pk + stoff[i],
                          (char*)lds + bsel * (BUF_SHORTS * 2) + (s << 10));
        }
    };

    stage(0, 0);
    __syncthreads();

    for (int kk = 0; kk < 4; ++kk) {
        const int cur = kk & 1;
        if (kk < 3) stage(kk + 1, cur ^ 1);     // prefetch next chunk

        const short* apb = Wt2s + ((ohf * 16 + kk) << 9) + (lane << 3);
        const short* bb  = lds + cur * BUF_SHORTS + (hp * 2) * ROW_SHORTS;
#pragma unroll
        for (int kx = 0; kx < 5; ++kx) {
            const int nky = (kx < 3) ? 3 : 2;   // ky=2 only for kx<3
            short8 B[4][4];                     // [row][ni], rolling fill
#pragma unroll
            for (int ni = 0; ni < 4; ++ni) {
                B[0][ni] = *reinterpret_cast<const short8*>(
                    bb + 0 * ROW_SHORTS + bq[kx] + ni * 512);
                B[1][ni] = *reinterpret_cast<const short8*>(
                    bb + 1 * ROW_SHORTS + bq[kx] + ni * 512);
            }
#pragma unroll
            for (int ky = 0; ky < 3; ++ky) {
                if (ky >= nky) break;
                if (ky + 2 <= nky) {
#pragma unroll
                    for (int ni = 0; ni < 4; ++ni)
                        B[ky + 2][ni] = *reinterpret_cast<const short8*>(
                            bb + (ky + 2) * ROW_SHORTS + bq[kx] + ni * 512);
                }
                const short* ap = apb + (ky * 5 + kx) * 16384;
                short8 a[4];
#pragma unroll
                for (int mi = 0; mi < 4; ++mi)
                    a[mi] = *reinterpret_cast<const short8*>(ap + mi * 2048);
                __builtin_amdgcn_s_setprio(1);
#pragma unroll
                for (int mi = 0; mi < 4; ++mi)
#pragma unroll
                    for (int o = 0; o < 2; ++o)
#pragma unroll
                        for (int ni = 0; ni < 4; ++ni)
                            acc[mi][o][ni] = __builtin_amdgcn_mfma_f32_16x16x32_bf16(
                                a[mi], B[ky + o][ni], acc[mi][o][ni], 0, 0, 0);
                __builtin_amdgcn_s_setprio(0);
            }
        }
        __syncthreads();   // drains prefetch + protects buf reuse
    }

    // ---- epilogue: bias + per-channel leaky relu ----------------------------
#pragma unroll
    for (int mi = 0; mi < 4; ++mi) {
        int ocb = ohf * 64 + mi * 16 + 4 * khi;
        f32x4 b4 = *reinterpret_cast<const f32x4*>(bias + ocb);
        f32x4 s4 = *reinterpret_cast<const f32x4*>(slope + ocb);
#pragma unroll
        for (int o = 0; o < 2; ++o) {
            int hrow = h0 + hp * 2 + o;
#pragma unroll
            for (int i = 0; i < 4; ++i) {
                float* orow = outn + ((ocb + i) * H + hrow) * W + w0 + pxh * 64;
#pragma unroll
                for (int ni = 0; ni < 4; ++ni) {
                    float v = acc[mi][o][ni][i] + b4[i];
                    v = v > 0.f ? v : s4[i] * v;
                    orow[ni * 16 + l15] = v;
                }
            }
        }
    }
}

extern "C" void kernel_launch(void* const* d_in, const int* in_sizes, int n_in,
                              void* d_out, int out_size, void* d_ws, size_t ws_size,
                              hipStream_t stream) {
    const float* x      = (const float*)d_in[0];
    const float* weight = (const float*)d_in[1];
    const float* bias   = (const float*)d_in[2];
    const float* slope  = (const float*)d_in[3];
    float* out = (float*)d_out;

    __hip_bfloat16* Pbase = (__hip_bfloat16*)d_ws;                 // 8 slabs
    __hip_bfloat16* Wt2   = (__hip_bfloat16*)((char*)d_ws + 8 * (size_t)P_BYTES);

    zero_pads<<<dim3(PH, 8), 256, 0, stream>>>((unsigned int*)d_ws);
    premask_weights<<<832, 256, 0, stream>>>(weight, Wt2);
    transpose_pad_all<<<dim3(64, 256, 8), 256, 0, stream>>>(x, Pbase);
    conv_mfma_all<<<2048, 512, 0, stream>>>(Pbase, Wt2, bias, slope, out);
}